// Round 2
// baseline (410.891 us; speedup 1.0000x reference)
//
#include <hip/hip_runtime.h>
#include <math.h>

#define T_TOK 4096
#define DM 1024
#define HID 4096
#define NEXP 8

typedef unsigned short u16;
typedef __attribute__((ext_vector_type(8))) short short8;
typedef __attribute__((ext_vector_type(4))) float f32x4;

__device__ __forceinline__ u16 f2bf(float f){
  unsigned u = __float_as_uint(f);
  u += 0x7FFF + ((u >> 16) & 1);
  return (u16)(u >> 16);
}

// ---- workspace layout (byte offsets) ----
#define GATE_OFF   0u          // float[4096]
#define CNT_OFF    16384u      // int[8]
#define LIST_OFF   16512u      // int[8][4096]
#define PROBS_OFF  147584u     // float[4096][8]
#define XB_OFF     278656u     // bf16[4096][1024]
#define H_OFF      8667264u    // bf16[4096][4096]
#define W1B_OFF    42221696u   // bf16[8][4096][1024]
#define W2B_OFF    109330560u  // bf16[8][1024][4096]
#define WS_NEED_BF 176439424u

__device__ __forceinline__ void glds16(const void* g, void* l){
  __builtin_amdgcn_global_load_lds((const __attribute__((address_space(1))) void*)g,
                                   (__attribute__((address_space(3))) void*)l, 16, 0, 0);
}

__global__ void zero_cnt_kernel(int* cnt){
  if (threadIdx.x < NEXP) cnt[threadIdx.x] = 0;
}

// fp32 -> bf16 streaming convert, 8 elems/thread
__global__ __launch_bounds__(256) void cvt_kernel(const float* __restrict__ src,
                                                  u16* __restrict__ dst){
  size_t i = (size_t)blockIdx.x * 256 + threadIdx.x;
  const float4* s = (const float4*)src + i * 2;
  float4 a = s[0], b = s[1];
  uint4 p;
  p.x = (unsigned)f2bf(a.x) | ((unsigned)f2bf(a.y) << 16);
  p.y = (unsigned)f2bf(a.z) | ((unsigned)f2bf(a.w) << 16);
  p.z = (unsigned)f2bf(b.x) | ((unsigned)f2bf(b.y) << 16);
  p.w = (unsigned)f2bf(b.z) | ((unsigned)f2bf(b.w) << 16);
  ((uint4*)dst)[i] = p;
}

// one wave per token: gating + routing + x->bf16 conversion
__global__ __launch_bounds__(256) void gate_kernel(
    const float* __restrict__ x, const float* __restrict__ gw,
    float* __restrict__ gateo, int* __restrict__ cnt, int* __restrict__ list,
    float* __restrict__ probs, u16* __restrict__ xb)
{
  int tid = threadIdx.x;
  int lane = tid & 63;
  int w = tid >> 6;
  int t = blockIdx.x * 4 + w;

  const float4* x4 = (const float4*)(x + (size_t)t * DM);
  const float4* g4 = (const float4*)gw;

  float acc[8] = {0,0,0,0,0,0,0,0};
  #pragma unroll
  for (int i = 0; i < 4; i++){
    int p = i * 64 + lane;
    float4 xv = x4[p];
    ushort4 pk;
    pk.x = f2bf(xv.x); pk.y = f2bf(xv.y); pk.z = f2bf(xv.z); pk.w = f2bf(xv.w);
    *(ushort4*)&xb[(size_t)t * DM + (size_t)p * 4] = pk;
    #pragma unroll
    for (int e = 0; e < NEXP; e++){
      float4 gv = g4[e * 256 + p];
      acc[e] += xv.x * gv.x + xv.y * gv.y + xv.z * gv.z + xv.w * gv.w;
    }
  }
  #pragma unroll
  for (int e = 0; e < NEXP; e++){
    #pragma unroll
    for (int off = 32; off; off >>= 1)
      acc[e] += __shfl_xor(acc[e], off);
  }
  if (lane == 0){
    float mx = acc[0];
    #pragma unroll
    for (int e = 1; e < NEXP; e++) mx = fmaxf(mx, acc[e]);
    float p[8]; float s = 0.f;
    #pragma unroll
    for (int e = 0; e < NEXP; e++){ p[e] = expf(acc[e] - mx); s += p[e]; }
    float inv = 1.f / s;
    int be = 0; float bp = p[0];
    #pragma unroll
    for (int e = 1; e < NEXP; e++){ if (p[e] > bp){ bp = p[e]; be = e; } }
    #pragma unroll
    for (int e = 0; e < NEXP; e++) probs[(size_t)t * 8 + e] = p[e] * inv;
    gateo[t] = bp * inv;
    int pos = atomicAdd(&cnt[be], 1);
    list[be * T_TOK + pos] = t;
  }
}

// deterministic aux-loss reduction, one block
__global__ __launch_bounds__(256) void aux_kernel(
    const float* __restrict__ probs, const int* __restrict__ cnt,
    float* __restrict__ aux_out)
{
  __shared__ float sm[256 * 8];
  int tid = threadIdx.x;
  float s[8] = {0,0,0,0,0,0,0,0};
  for (int i = 0; i < 16; i++){
    int t = i * 256 + tid;
    #pragma unroll
    for (int e = 0; e < 8; e++) s[e] += probs[(size_t)t * 8 + e];
  }
  #pragma unroll
  for (int e = 0; e < 8; e++) sm[tid * 8 + e] = s[e];
  __syncthreads();
  for (int st = 128; st; st >>= 1){
    if (tid < st){
      #pragma unroll
      for (int e = 0; e < 8; e++) sm[tid * 8 + e] += sm[(tid + st) * 8 + e];
    }
    __syncthreads();
  }
  if (tid == 0){
    float a = 0.f;
    #pragma unroll
    for (int e = 0; e < 8; e++){
      float f = (float)cnt[e] / (float)T_TOK;
      float P = sm[e] / (float)T_TOK;
      a += f * P;
    }
    aux_out[0] = 0.01f * (float)NEXP * a;
  }
}

// grouped GEMM, 128x128 tile, BK=64, double-buffered LDS, global_load_lds staging.
// BBF16: B already bf16 in Bb. else: reg-stage fp32 Bf -> bf16 (pipelined).
// PHASE2=false: A=xb, B=w1 -> h = gelu(acc+b1) bf16
// PHASE2=true : A=h,  B=w2 -> out = gate*(acc+b2) fp32 scatter
template<int KT, int NTOT, bool PHASE2, bool BBF16>
__global__ __launch_bounds__(256, 2) void ffn_gemm(
    const u16*  __restrict__ Aall,   // [4096][KT] bf16
    const u16*  __restrict__ Bb,     // [E][NTOT][KT] bf16 (if BBF16)
    const float* __restrict__ Bf,    // [E][NTOT][KT] fp32 (if !BBF16)
    const float* __restrict__ bias,  // [E][NTOT]
    const int*  __restrict__ cnt,
    const int*  __restrict__ list,   // [E][4096]
    const float* __restrict__ gate,  // [4096]
    u16*  __restrict__ hOut,
    float* __restrict__ yOut)
{
  constexpr int NT = NTOT / 128;
  constexpr int KS = KT / 64;
  int bid = blockIdx.x;
  int e  = bid / (32 * NT);
  int r  = bid % (32 * NT);
  int mt = r / NT, nt = r % NT;
  int ne = cnt[e];
  int m0 = mt * 128;
  if (m0 >= ne) return;
  const int* lst = list + e * T_TOK;
  int n0 = nt * 128;

  __shared__ u16 As[2][8192];   // [128][64]
  __shared__ u16 Bs[2][8192];

  int tid  = threadIdx.x;
  int lane = tid & 63;
  int w    = tid >> 6;
  int wr = (w >> 1) * 64, wc = (w & 1) * 64;
  int fr = lane & 15, fq = lane >> 4;

  // glds staging: wave w owns segments w*4..w*4+3; seg covers rows [seg*8, seg*8+8)
  // lane l -> row seg*8 + (l>>3), 16B chunk l&7. LDS dest = seg*512 (wave-uniform).
  const u16* aS[4];
  const u16* bS[4];
  #pragma unroll
  for (int i = 0; i < 4; i++){
    int seg = w * 4 + i;
    int row = seg * 8 + (lane >> 3);
    int ch  = lane & 7;
    int mrow = m0 + row; if (mrow > ne - 1) mrow = ne - 1;
    aS[i] = Aall + (size_t)lst[mrow] * KT + ch * 8;
    if (BBF16) bS[i] = Bb + (size_t)e * NTOT * KT + (size_t)(n0 + row) * KT + ch * 8;
  }
  // fp32 fallback staging ownership (8 bf16 per thread-slot, 4 slots)
  const float* fS[4]; int fD[4];
  if (!BBF16){
    #pragma unroll
    for (int i = 0; i < 4; i++){
      int idx = i * 256 + tid;
      int row = idx >> 3, ch = idx & 7;
      fS[i] = Bf + (size_t)e * NTOT * KT + (size_t)(n0 + row) * KT + ch * 8;
      fD[i] = row * 64 + ch * 8;
    }
  }

  f32x4 acc[4][4];
  #pragma unroll
  for (int m = 0; m < 4; m++)
    #pragma unroll
    for (int n = 0; n < 4; n++)
      acc[m][n] = (f32x4){0.f, 0.f, 0.f, 0.f};

  // prologue: stage ks=0 into buf 0
  #pragma unroll
  for (int i = 0; i < 4; i++){
    int seg = w * 4 + i;
    glds16(aS[i], &As[0][seg * 512]);
    if (BBF16) glds16(bS[i], &Bs[0][seg * 512]);
  }
  if (!BBF16){
    #pragma unroll
    for (int i = 0; i < 4; i++){
      float4 f0 = ((const float4*)fS[i])[0], f1 = ((const float4*)fS[i])[1];
      uint4 p;
      p.x = (unsigned)f2bf(f0.x) | ((unsigned)f2bf(f0.y) << 16);
      p.y = (unsigned)f2bf(f0.z) | ((unsigned)f2bf(f0.w) << 16);
      p.z = (unsigned)f2bf(f1.x) | ((unsigned)f2bf(f1.y) << 16);
      p.w = (unsigned)f2bf(f1.z) | ((unsigned)f2bf(f1.w) << 16);
      *(uint4*)&Bs[0][fD[i]] = p;
    }
  }
  __syncthreads();

  int buf = 0;
  for (int ks = 0; ks < KS; ++ks){
    int nxt = ks + 1;
    float4 pf0[4], pf1[4];
    if (nxt < KS){
      if (!BBF16){
        #pragma unroll
        for (int i = 0; i < 4; i++){
          const float4* s = (const float4*)(fS[i] + nxt * 64);
          pf0[i] = s[0]; pf1[i] = s[1];
        }
      }
      #pragma unroll
      for (int i = 0; i < 4; i++){
        int seg = w * 4 + i;
        glds16(aS[i] + nxt * 64, &As[buf ^ 1][seg * 512]);
        if (BBF16) glds16(bS[i] + nxt * 64, &Bs[buf ^ 1][seg * 512]);
      }
    }
    // compute current buffer
    #pragma unroll
    for (int kc = 0; kc < 2; kc++){
      short8 a[4], b[4];
      #pragma unroll
      for (int m = 0; m < 4; m++)
        a[m] = *(const short8*)&As[buf][(wr + m * 16 + fr) * 64 + (kc * 4 + fq) * 8];
      #pragma unroll
      for (int n = 0; n < 4; n++)
        b[n] = *(const short8*)&Bs[buf][(wc + n * 16 + fr) * 64 + (kc * 4 + fq) * 8];
      #pragma unroll
      for (int m = 0; m < 4; m++)
        #pragma unroll
        for (int n = 0; n < 4; n++)
          acc[m][n] = __builtin_amdgcn_mfma_f32_16x16x32_bf16(a[m], b[n], acc[m][n], 0, 0, 0);
    }
    if (nxt < KS && !BBF16){
      #pragma unroll
      for (int i = 0; i < 4; i++){
        uint4 p;
        p.x = (unsigned)f2bf(pf0[i].x) | ((unsigned)f2bf(pf0[i].y) << 16);
        p.y = (unsigned)f2bf(pf0[i].z) | ((unsigned)f2bf(pf0[i].w) << 16);
        p.z = (unsigned)f2bf(pf1[i].x) | ((unsigned)f2bf(pf1[i].y) << 16);
        p.w = (unsigned)f2bf(pf1[i].z) | ((unsigned)f2bf(pf1[i].w) << 16);
        *(uint4*)&Bs[buf ^ 1][fD[i]] = p;
      }
    }
    __syncthreads();
    buf ^= 1;
  }

  // epilogue: C frag layout col = lane&15, row = (lane>>4)*4 + i
  #pragma unroll
  for (int n = 0; n < 4; n++){
    int col = n0 + wc + n * 16 + fr;
    float bv = bias[(size_t)e * NTOT + col];
    #pragma unroll
    for (int m = 0; m < 4; m++){
      int rbase = m0 + wr + m * 16 + fq * 4;
      f32x4 v = acc[m][n];
      #pragma unroll
      for (int i = 0; i < 4; i++){
        int mrow = rbase + i;
        if (mrow < ne){
          int tok = lst[mrow];
          float val = v[i] + bv;
          if (PHASE2){
            yOut[(size_t)tok * NTOT + col] = gate[tok] * val;
          } else {
            float gl = 0.5f * val * (1.0f + erff(val * 0.70710678118654752f));
            hOut[(size_t)tok * NTOT + col] = f2bf(gl);
          }
        }
      }
    }
  }
}

extern "C" void kernel_launch(void* const* d_in, const int* in_sizes, int n_in,
                              void* d_out, int out_size, void* d_ws, size_t ws_size,
                              hipStream_t stream) {
  const float* x   = (const float*)d_in[0];
  const float* gw  = (const float*)d_in[1];
  const float* w1  = (const float*)d_in[2];
  const float* b1  = (const float*)d_in[3];
  const float* w2  = (const float*)d_in[4];
  const float* b2  = (const float*)d_in[5];

  char* ws = (char*)d_ws;
  float* gateo = (float*)(ws + GATE_OFF);
  int*   cnt   = (int*)  (ws + CNT_OFF);
  int*   list  = (int*)  (ws + LIST_OFF);
  float* probs = (float*)(ws + PROBS_OFF);
  u16*   xb    = (u16*)  (ws + XB_OFF);
  u16*   h     = (u16*)  (ws + H_OFF);
  u16*   w1b   = (u16*)  (ws + W1B_OFF);
  u16*   w2b   = (u16*)  (ws + W2B_OFF);

  float* out = (float*)d_out;
  float* aux = out + (size_t)T_TOK * DM;

  bool useBF = ws_size >= (size_t)WS_NEED_BF;

  hipLaunchKernelGGL(zero_cnt_kernel, dim3(1), dim3(64), 0, stream, cnt);
  if (useBF){
    hipLaunchKernelGGL(cvt_kernel, dim3(16384), dim3(256), 0, stream, w1, w1b);
    hipLaunchKernelGGL(cvt_kernel, dim3(16384), dim3(256), 0, stream, w2, w2b);
  }
  hipLaunchKernelGGL(gate_kernel, dim3(T_TOK / 4), dim3(256), 0, stream,
                     x, gw, gateo, cnt, list, probs, xb);
  hipLaunchKernelGGL(aux_kernel, dim3(1), dim3(256), 0, stream, probs, cnt, aux);

  if (useBF){
    hipLaunchKernelGGL((ffn_gemm<DM, HID, false, true>), dim3(NEXP * 32 * (HID / 128)), dim3(256), 0, stream,
                       xb, w1b, (const float*)nullptr, b1, cnt, list, gateo, h, (float*)nullptr);
    hipLaunchKernelGGL((ffn_gemm<HID, DM, true, true>), dim3(NEXP * 32 * (DM / 128)), dim3(256), 0, stream,
                       h, w2b, (const float*)nullptr, b2, cnt, list, gateo, (u16*)nullptr, out);
  } else {
    hipLaunchKernelGGL((ffn_gemm<DM, HID, false, false>), dim3(NEXP * 32 * (HID / 128)), dim3(256), 0, stream,
                       xb, (const u16*)nullptr, w1, b1, cnt, list, gateo, h, (float*)nullptr);
    hipLaunchKernelGGL((ffn_gemm<HID, DM, true, false>), dim3(NEXP * 32 * (DM / 128)), dim3(256), 0, stream,
                       h, (const u16*)nullptr, w2, b2, cnt, list, gateo, (u16*)nullptr, out);
  }
}

// Round 3
// 370.482 us; speedup vs baseline: 1.1091x; 1.1091x over previous
//
#include <hip/hip_runtime.h>
#include <math.h>

#define T_TOK 4096
#define DM 1024
#define HID 4096
#define NEXP 8

typedef unsigned short u16;
typedef __attribute__((ext_vector_type(8))) short short8;
typedef __attribute__((ext_vector_type(4))) float f32x4;

__device__ __forceinline__ u16 f2bf(float f){
  unsigned u = __float_as_uint(f);
  u += 0x7FFF + ((u >> 16) & 1);
  return (u16)(u >> 16);
}

// ---- workspace layout (byte offsets) ----
#define GATE_OFF   0u          // float[4096]
#define CNT_OFF    16384u      // int[8]
#define LIST_OFF   16512u      // int[8][4096]
#define PROBS_OFF  147584u     // float[4096][8]
#define XB_OFF     278656u     // bf16[4096][1024]
#define H_OFF      8667264u    // bf16[4096][4096]
#define W1B_OFF    42221696u   // bf16[8][4096][1024]  (reused as PART after GEMM1)
#define PART_OFF   W1B_OFF     // float[4][4096][1024] = 64MB, exact overlay of w1b
#define W2B_OFF    109330560u  // bf16[8][1024][4096]
#define WS_NEED_BF 176439424u

__device__ __forceinline__ void glds16(const void* g, void* l){
  __builtin_amdgcn_global_load_lds((const __attribute__((address_space(1))) void*)g,
                                   (__attribute__((address_space(3))) void*)l, 16, 0, 0);
}

__global__ void zero_cnt_kernel(int* cnt){
  if (threadIdx.x < NEXP) cnt[threadIdx.x] = 0;
}

// fp32 -> bf16 streaming convert, 8 elems/thread
__global__ __launch_bounds__(256) void cvt_kernel(const float* __restrict__ src,
                                                  u16* __restrict__ dst){
  size_t i = (size_t)blockIdx.x * 256 + threadIdx.x;
  const float4* s = (const float4*)src + i * 2;
  float4 a = s[0], b = s[1];
  uint4 p;
  p.x = (unsigned)f2bf(a.x) | ((unsigned)f2bf(a.y) << 16);
  p.y = (unsigned)f2bf(a.z) | ((unsigned)f2bf(a.w) << 16);
  p.z = (unsigned)f2bf(b.x) | ((unsigned)f2bf(b.y) << 16);
  p.w = (unsigned)f2bf(b.z) | ((unsigned)f2bf(b.w) << 16);
  ((uint4*)dst)[i] = p;
}

// one wave per token: gating + routing + x->bf16 conversion
__global__ __launch_bounds__(256) void gate_kernel(
    const float* __restrict__ x, const float* __restrict__ gw,
    float* __restrict__ gateo, int* __restrict__ cnt, int* __restrict__ list,
    float* __restrict__ probs, u16* __restrict__ xb)
{
  int tid = threadIdx.x;
  int lane = tid & 63;
  int w = tid >> 6;
  int t = blockIdx.x * 4 + w;

  const float4* x4 = (const float4*)(x + (size_t)t * DM);
  const float4* g4 = (const float4*)gw;

  float acc[8] = {0,0,0,0,0,0,0,0};
  #pragma unroll
  for (int i = 0; i < 4; i++){
    int p = i * 64 + lane;
    float4 xv = x4[p];
    ushort4 pk;
    pk.x = f2bf(xv.x); pk.y = f2bf(xv.y); pk.z = f2bf(xv.z); pk.w = f2bf(xv.w);
    *(ushort4*)&xb[(size_t)t * DM + (size_t)p * 4] = pk;
    #pragma unroll
    for (int e = 0; e < NEXP; e++){
      float4 gv = g4[e * 256 + p];
      acc[e] += xv.x * gv.x + xv.y * gv.y + xv.z * gv.z + xv.w * gv.w;
    }
  }
  #pragma unroll
  for (int e = 0; e < NEXP; e++){
    #pragma unroll
    for (int off = 32; off; off >>= 1)
      acc[e] += __shfl_xor(acc[e], off);
  }
  if (lane == 0){
    float mx = acc[0];
    #pragma unroll
    for (int e = 1; e < NEXP; e++) mx = fmaxf(mx, acc[e]);
    float p[8]; float s = 0.f;
    #pragma unroll
    for (int e = 0; e < NEXP; e++){ p[e] = expf(acc[e] - mx); s += p[e]; }
    float inv = 1.f / s;
    int be = 0; float bp = p[0];
    #pragma unroll
    for (int e = 1; e < NEXP; e++){ if (p[e] > bp){ bp = p[e]; be = e; } }
    #pragma unroll
    for (int e = 0; e < NEXP; e++) probs[(size_t)t * 8 + e] = p[e] * inv;
    gateo[t] = bp * inv;
    int pos = atomicAdd(&cnt[be], 1);
    list[be * T_TOK + pos] = t;
  }
}

// deterministic aux-loss reduction, one block
__global__ __launch_bounds__(256) void aux_kernel(
    const float* __restrict__ probs, const int* __restrict__ cnt,
    float* __restrict__ aux_out)
{
  __shared__ float sm[256 * 8];
  int tid = threadIdx.x;
  float s[8] = {0,0,0,0,0,0,0,0};
  for (int i = 0; i < 16; i++){
    int t = i * 256 + tid;
    #pragma unroll
    for (int e = 0; e < 8; e++) s[e] += probs[(size_t)t * 8 + e];
  }
  #pragma unroll
  for (int e = 0; e < 8; e++) sm[tid * 8 + e] = s[e];
  __syncthreads();
  for (int st = 128; st; st >>= 1){
    if (tid < st){
      #pragma unroll
      for (int e = 0; e < 8; e++) sm[tid * 8 + e] += sm[(tid + st) * 8 + e];
    }
    __syncthreads();
  }
  if (tid == 0){
    float a = 0.f;
    #pragma unroll
    for (int e = 0; e < 8; e++){
      float f = (float)cnt[e] / (float)T_TOK;
      float P = sm[e] / (float)T_TOK;
      a += f * P;
    }
    aux_out[0] = 0.01f * (float)NEXP * a;
  }
}

// grouped GEMM, 256x256 tile, BK=64, 8 waves (2Mx4N), double-buffered LDS,
// global_load_lds with pre-swizzled source + XOR-swizzled ds_read.
// Per-block K depth fixed at 1024 (GEMM2 uses NSPLIT=4 split-K partials).
// PHASE2=false: A=xb, B=w1b -> h = gelu(acc+b1) bf16
// PHASE2=true : A=h,  B=w2b -> part[sk][tok][col] = acc (+b2 if sk==0) fp32
template<int NTOT, int ASTR, int BSTR, int NSPLIT, bool PHASE2>
__global__ __launch_bounds__(512, 2) void ffn_gemm(
    const u16*  __restrict__ Aall,
    const u16*  __restrict__ Bb,
    const float* __restrict__ bias,
    const int*  __restrict__ cnt,
    const int*  __restrict__ list,
    u16*  __restrict__ hOut,
    float* __restrict__ pOut)
{
  constexpr int NT = NTOT / 256;
  constexpr int KS = 16;                 // 1024 / 64
  int bid = blockIdx.x;
  int nt = bid % NT;
  int t1 = bid / NT;
  int sk = t1 % NSPLIT;
  int t2 = t1 / NSPLIT;
  int mt = t2 % 16;
  int e  = t2 / 16;
  int ne = cnt[e];
  int m0 = mt * 256;
  if (m0 >= ne) return;
  const int* lst = list + e * T_TOK;
  int n0 = nt * 256;
  int koff = sk * 1024;

  __shared__ u16 As[2][16384];   // [256][64]
  __shared__ u16 Bs[2][16384];

  int tid  = threadIdx.x;
  int lane = tid & 63;
  int w    = tid >> 6;
  int wm = w >> 2, wn = w & 3;          // 2M x 4N wave grid
  int fr = lane & 15, fq = lane >> 4;

  // staging: 32 segments (8 rows x 64 cols = 1KB each) per matrix; wave w owns 4.
  // lane l -> row seg*8+(l>>3), slot l&7; global source chunk g = (l&7)^(row&7)
  // so LDS[row][slot] holds global chunk slot^(row&7)  (rule #21: inv-swz source)
  const u16* aS[4]; const u16* bS[4];
  #pragma unroll
  for (int i = 0; i < 4; i++){
    int seg = w * 4 + i;
    int r   = seg * 8 + (lane >> 3);
    int g   = (lane & 7) ^ (r & 7);
    int mrow = m0 + r; if (mrow > ne - 1) mrow = ne - 1;
    aS[i] = Aall + (size_t)lst[mrow] * ASTR + koff + g * 8;
    bS[i] = Bb + (size_t)e * NTOT * BSTR + (size_t)(n0 + r) * BSTR + koff + g * 8;
  }

  f32x4 acc[8][4];
  #pragma unroll
  for (int m = 0; m < 8; m++)
    #pragma unroll
    for (int n = 0; n < 4; n++)
      acc[m][n] = (f32x4){0.f, 0.f, 0.f, 0.f};

  // prologue: stage K-step 0 into buf 0
  #pragma unroll
  for (int i = 0; i < 4; i++){
    int seg = w * 4 + i;
    glds16(aS[i], &As[0][seg * 512]);
    glds16(bS[i], &Bs[0][seg * 512]);
  }
  __syncthreads();

  int buf = 0;
  for (int ks = 0; ks < KS; ++ks){
    if (ks + 1 < KS){
      #pragma unroll
      for (int i = 0; i < 4; i++){
        int seg = w * 4 + i;
        glds16(aS[i] + (ks + 1) * 64, &As[buf ^ 1][seg * 512]);
        glds16(bS[i] + (ks + 1) * 64, &Bs[buf ^ 1][seg * 512]);
      }
    }
    #pragma unroll
    for (int kc = 0; kc < 2; kc++){
      short8 a[8], b[4];
      #pragma unroll
      for (int m = 0; m < 8; m++){
        int row  = wm * 128 + m * 16 + fr;
        int slot = (kc * 4 + fq) ^ (row & 7);
        a[m] = *(const short8*)&As[buf][row * 64 + slot * 8];
      }
      #pragma unroll
      for (int n = 0; n < 4; n++){
        int row  = wn * 64 + n * 16 + fr;
        int slot = (kc * 4 + fq) ^ (row & 7);
        b[n] = *(const short8*)&Bs[buf][row * 64 + slot * 8];
      }
      #pragma unroll
      for (int m = 0; m < 8; m++)
        #pragma unroll
        for (int n = 0; n < 4; n++)
          acc[m][n] = __builtin_amdgcn_mfma_f32_16x16x32_bf16(a[m], b[n], acc[m][n], 0, 0, 0);
    }
    __syncthreads();
    buf ^= 1;
  }

  // epilogue: C frag layout col = lane&15, row = (lane>>4)*4 + i
  #pragma unroll
  for (int n = 0; n < 4; n++){
    int col = n0 + wn * 64 + n * 16 + fr;
    float bv = bias[(size_t)e * NTOT + col];
    if (PHASE2 && sk != 0) bv = 0.f;
    #pragma unroll
    for (int m = 0; m < 8; m++){
      int rbase = m0 + wm * 128 + m * 16 + fq * 4;
      f32x4 v = acc[m][n];
      #pragma unroll
      for (int i = 0; i < 4; i++){
        int mrow = rbase + i;
        if (mrow < ne){
          int tok = lst[mrow];
          float val = v[i] + bv;
          if (PHASE2){
            pOut[((size_t)sk * T_TOK + tok) * DM + col] = val;
          } else {
            float gl = 0.5f * val * (1.0f + erff(val * 0.70710678118654752f));
            hOut[(size_t)tok * NTOT + col] = f2bf(gl);
          }
        }
      }
    }
  }
}

// sum 4 split-K partials, apply gate, write fp32 out
__global__ __launch_bounds__(256) void reduce_kernel(
    const float* __restrict__ part, const float* __restrict__ gate,
    float* __restrict__ out)
{
  size_t i = (size_t)blockIdx.x * 256 + threadIdx.x;     // float4 index
  constexpr size_t S = (size_t)T_TOK * DM / 4;
  const float4* p = (const float4*)part;
  float4 a = p[i], b = p[i + S], c = p[i + 2 * S], d = p[i + 3 * S];
  float g = gate[i >> 8];                                // 256 float4 per row
  float4 o;
  o.x = (a.x + b.x + c.x + d.x) * g;
  o.y = (a.y + b.y + c.y + d.y) * g;
  o.z = (a.z + b.z + c.z + d.z) * g;
  o.w = (a.w + b.w + c.w + d.w) * g;
  ((float4*)out)[i] = o;
}

extern "C" void kernel_launch(void* const* d_in, const int* in_sizes, int n_in,
                              void* d_out, int out_size, void* d_ws, size_t ws_size,
                              hipStream_t stream) {
  const float* x   = (const float*)d_in[0];
  const float* gw  = (const float*)d_in[1];
  const float* w1  = (const float*)d_in[2];
  const float* b1  = (const float*)d_in[3];
  const float* w2  = (const float*)d_in[4];
  const float* b2  = (const float*)d_in[5];

  char* ws = (char*)d_ws;
  float* gateo = (float*)(ws + GATE_OFF);
  int*   cnt   = (int*)  (ws + CNT_OFF);
  int*   list  = (int*)  (ws + LIST_OFF);
  float* probs = (float*)(ws + PROBS_OFF);
  u16*   xb    = (u16*)  (ws + XB_OFF);
  u16*   h     = (u16*)  (ws + H_OFF);
  u16*   w1b   = (u16*)  (ws + W1B_OFF);
  float* part  = (float*)(ws + PART_OFF);   // overlays w1b (dead after GEMM1)
  u16*   w2b   = (u16*)  (ws + W2B_OFF);

  float* out = (float*)d_out;
  float* aux = out + (size_t)T_TOK * DM;

  hipLaunchKernelGGL(zero_cnt_kernel, dim3(1), dim3(64), 0, stream, cnt);
  hipLaunchKernelGGL(cvt_kernel, dim3(16384), dim3(256), 0, stream, w1, w1b);
  hipLaunchKernelGGL(cvt_kernel, dim3(16384), dim3(256), 0, stream, w2, w2b);
  hipLaunchKernelGGL(gate_kernel, dim3(T_TOK / 4), dim3(256), 0, stream,
                     x, gw, gateo, cnt, list, probs, xb);
  hipLaunchKernelGGL(aux_kernel, dim3(1), dim3(256), 0, stream, probs, cnt, aux);

  // GEMM1: [tok,1024] x w1b[e][4096][1024] -> h[tok][4096]
  hipLaunchKernelGGL((ffn_gemm<HID, DM, DM, 1, false>),
                     dim3(NEXP * 16 * (HID / 256)), dim3(512), 0, stream,
                     xb, w1b, b1, cnt, list, h, (float*)nullptr);
  // GEMM2: [tok,4096] x w2b[e][1024][4096] -> part[sk][tok][1024], split-K=4
  hipLaunchKernelGGL((ffn_gemm<DM, HID, HID, 4, true>),
                     dim3(NEXP * 16 * (DM / 256) * 4), dim3(512), 0, stream,
                     h, w2b, b2, cnt, list, (u16*)nullptr, part);
  hipLaunchKernelGGL(reduce_kernel, dim3(T_TOK * DM / 4 / 256), dim3(256), 0, stream,
                     part, gateo, out);
}